// Round 8
// baseline (165.567 us; speedup 1.0000x reference)
//
#include <hip/hip_runtime.h>
#include <hip/hip_bf16.h>

#define S_NODES 8192
#define P_PATHS 16
#define K_EP    16
#define D_DIM   128
#define H_DIM   64

typedef __bf16 bf16x8_t __attribute__((ext_vector_type(8)));
typedef float  f32x4_t  __attribute__((ext_vector_type(4)));

// LDS strides (elements per row), hot accesses <=2-way bank aliased (free):
#define AGGF_STRIDE  132   // floats
#define AGGBF_STRIDE 136   // bf16; rows 272B, 16B-aligned for b128 A-frag reads

// ---- fused prep: out=0, entity fp32->bf16 (+1 zero pad row), W1 -> W1^T bf16 ----
// NT on single-use streams (ent fp32 read, out zero-store) to keep L2/L3 for the
// bf16 table the main kernel is about to hammer. NOTE: nontemporal builtins need
// ext_vector types (f32x4_t), not HIP_vector_type (float4).
__global__ __launch_bounds__(256)
void prep_fused_kernel(const float* __restrict__ ent, const float* __restrict__ W1,
                       __bf16* __restrict__ entbf, __bf16* __restrict__ w1t,
                       float* __restrict__ out, int n4, int o4)
{
    const int i = blockIdx.x * 256 + threadIdx.x;
    if (i < n4) {
        f32x4_t v = __builtin_nontemporal_load(((const f32x4_t*)ent) + i);
        union { __bf16 h[4]; uint2 u; } pk;
        pk.h[0] = (__bf16)v[0]; pk.h[1] = (__bf16)v[1];
        pk.h[2] = (__bf16)v[2]; pk.h[3] = (__bf16)v[3];
        ((uint2*)entbf)[i] = pk.u;          // cached: gather-read next kernel
    }
    if (i < 32)  // zero pad row at entity index N (256 B)
        ((uint2*)entbf)[n4 + i] = make_uint2(0u, 0u);
    if (i < o4) {
        const f32x4_t z = {0.f, 0.f, 0.f, 0.f};
        __builtin_nontemporal_store(z, ((f32x4_t*)out) + i);
    }
    if (i < D_DIM * H_DIM) {
        const int n = i >> 7, d = i & 127;
        w1t[i] = (__bf16)W1[d * H_DIM + n];
    }
}

// ---- fallback-path prep ----
__global__ __launch_bounds__(256)
void prep_w1_kernel(const float* __restrict__ W1, __bf16* __restrict__ w1t)
{
    const int idx = blockIdx.x * 256 + threadIdx.x;   // 32 x 256 = 8192
    const int n = idx >> 7, d = idx & 127;
    w1t[idx] = (__bf16)W1[d * H_DIM + n];
}

// unpack a 16B bf16x8 chunk into two fp32 float4 accumulators
__device__ __forceinline__ void acc_row(float4& lo, float4& hi, uint4 r)
{
    lo.x += __uint_as_float(r.x << 16); lo.y += __uint_as_float(r.x & 0xffff0000u);
    lo.z += __uint_as_float(r.y << 16); lo.w += __uint_as_float(r.y & 0xffff0000u);
    hi.x += __uint_as_float(r.z << 16); hi.y += __uint_as_float(r.z & 0xffff0000u);
    hi.z += __uint_as_float(r.w << 16); hi.w += __uint_as_float(r.w & 0xffff0000u);
}

template<bool USE_BF16>
__global__ __launch_bounds__(256, 4)   // cap 128 VGPR: room for 16-deep load window
void PathGuidedAggregator_kernel(const float*  __restrict__ ent,
                                 const __bf16* __restrict__ entbf,  // bf16 table + zero pad row (ws)
                                 const float*  __restrict__ b1,
                                 const float*  __restrict__ W2,
                                 const float*  __restrict__ b2,
                                 const int*    __restrict__ sids,
                                 const int*    __restrict__ eids,
                                 const void*   __restrict__ emask,
                                 const __bf16* __restrict__ w1t,    // [H][D] bf16 (ws)
                                 float*        __restrict__ out,
                                 int nent)                          // pad row index
{
    __shared__ float  aggf [P_PATHS][AGGF_STRIDE];   // fp32 agg (epilogue w*agg)
    __shared__ __bf16 aggbf[P_PATHS][AGGBF_STRIDE];  // bf16 agg (MFMA A operand)
    __shared__ int    cnts[P_PATHS];
    __shared__ int    comp[4][4][K_EP];              // fallback + bf16 id staging

    const int s    = blockIdx.x;
    const int tid  = threadIdx.x;
    const int wave = tid >> 6;
    const int lane = tid & 63;

    // ---- runtime detection of bool-mask storage: int32 / uint8 / float32 ----
    // (probe line is re-read by every block -> keep it cached, NOT nontemporal)
    const unsigned int* mw = (const unsigned int*)emask;
    unsigned int probe = mw[lane];
    const bool floatMask = (__ballot(probe == 0x3F800000u) != 0ULL);
    const bool byteMask  = !floatMask && (__ballot(probe > 1u) != 0ULL);

    // ---- one coalesced 64-lane load covers ids+mask for this wave's 4 paths ----
    // R14: ids/mask are single-use streams (33.6 MB/launch) -> NONTEMPORAL loads so
    // they don't evict gather-table rows from the 4MB/XCD L2 (FETCH_SIZE showed
    // ~87MB of table re-fetch; table is only 25.6MB).
    const int base = (s * P_PATHS + wave * 4) * K_EP;
    const int idv  = __builtin_nontemporal_load(eids + base + lane);
    int mk;
    if (floatMask)     mk = (__builtin_nontemporal_load(((const float*)emask) + base + lane) != 0.0f);
    else if (byteMask) mk = __builtin_nontemporal_load(((const unsigned char*)emask) + base + lane);
    else               mk = __builtin_nontemporal_load(((const int*)emask) + base + lane);
    const unsigned long long bits_all = __ballot(mk != 0);

    const int k16  = lane & 15;
    const int pgrp = lane >> 4;

    // compact valid ids; pad slots point at the zero row (bf16 path) so loads need no guards
    const unsigned int bits_p = (unsigned int)((bits_all >> (16 * pgrp)) & 0xFFFFu);
    comp[wave][pgrp][k16] = USE_BF16 ? nent : 0;
    if (mk) comp[wave][pgrp][__popc(bits_p & ((1u << k16) - 1u))] = idv;
    if (lane < 4) cnts[wave * 4 + lane] = __popc((unsigned int)((bits_all >> (16 * lane)) & 0xFFFFu));

    const int c0 = __popc((unsigned int)( bits_all        & 0xFFFFu));
    const int c1 = __popc((unsigned int)((bits_all >> 16) & 0xFFFFu));
    const int c2 = __popc((unsigned int)((bits_all >> 32) & 0xFFFFu));
    const int c3 = __popc((unsigned int)((bits_all >> 48) & 0xFFFFu));

    const int q   = lane >> 4;       // quarter: owns slots q, q+4, q+8, q+12
    const int c16 = lane & 15;

    if constexpr (USE_BF16) {
        // ---- R14 gather: rotated-butterfly + FORCED 16-deep load window.
        // R13's preload was silently sunk by the scheduler (VGPR stayed 48 ->
        // ~8 in flight, duration unchanged: hypothesis untested). The
        // sched_barrier(0) below pins all 16 loads BEFORE any unpack, forcing
        // ~16 outstanding loads per wave (VGPR should rise to ~110-128).
        //
        // Accumulator j of quarter q holds path (q^j); cross-quarter merge is a
        // 2-stage reduce-scatter butterfly (24 shuffles, zero selects).
        const uint4* __restrict__ entb = (const uint4*)entbf;
        float4 l0 = {0,0,0,0}, h0 = l0, l1 = l0, h1 = l0, l2 = l0, h2 = l0, l3 = l0, h3 = l0;

        uint4 rb[16];
        #pragma unroll
        for (int sl = 0; sl < 4; ++sl) {
            const int slot = q + 4 * sl;
            rb[4 * sl + 0] = entb[(size_t)comp[wave][q    ][slot] * 16 + c16];
            rb[4 * sl + 1] = entb[(size_t)comp[wave][q ^ 1][slot] * 16 + c16];
            rb[4 * sl + 2] = entb[(size_t)comp[wave][q ^ 2][slot] * 16 + c16];
            rb[4 * sl + 3] = entb[(size_t)comp[wave][q ^ 3][slot] * 16 + c16];
        }
        __builtin_amdgcn_sched_barrier(0);   // pin: no unpack hoisted above, no load sunk below
        #pragma unroll
        for (int sl = 0; sl < 4; ++sl) {
            acc_row(l0, h0, rb[4 * sl + 0]);
            acc_row(l1, h1, rb[4 * sl + 1]);
            acc_row(l2, h2, rb[4 * sl + 2]);
            acc_row(l3, h3, rb[4 * sl + 3]);
        }
        // reduce-scatter stage 1 (xor 16)
        l0.x += __shfl_xor(l1.x, 16); l0.y += __shfl_xor(l1.y, 16);
        l0.z += __shfl_xor(l1.z, 16); l0.w += __shfl_xor(l1.w, 16);
        h0.x += __shfl_xor(h1.x, 16); h0.y += __shfl_xor(h1.y, 16);
        h0.z += __shfl_xor(h1.z, 16); h0.w += __shfl_xor(h1.w, 16);
        l2.x += __shfl_xor(l3.x, 16); l2.y += __shfl_xor(l3.y, 16);
        l2.z += __shfl_xor(l3.z, 16); l2.w += __shfl_xor(l3.w, 16);
        h2.x += __shfl_xor(h3.x, 16); h2.y += __shfl_xor(h3.y, 16);
        h2.z += __shfl_xor(h3.z, 16); h2.w += __shfl_xor(h3.w, 16);
        // reduce-scatter stage 2 (xor 32)
        l0.x += __shfl_xor(l2.x, 32); l0.y += __shfl_xor(l2.y, 32);
        l0.z += __shfl_xor(l2.z, 32); l0.w += __shfl_xor(l2.w, 32);
        h0.x += __shfl_xor(h2.x, 32); h0.y += __shfl_xor(h2.y, 32);
        h0.z += __shfl_xor(h2.z, 32); h0.w += __shfl_xor(h2.w, 32);

        // quarter q now holds the full sum of path q in (l0, h0)
        const int   cq   = __popc((unsigned int)((bits_all >> (16 * q)) & 0xFFFFu));
        const float invq = 1.0f / (float)(cq > 1 ? cq : 1);
        l0.x *= invq; l0.y *= invq; l0.z *= invq; l0.w *= invq;
        h0.x *= invq; h0.y *= invq; h0.z *= invq; h0.w *= invq;
        const int pw = wave * 4 + q;
        *(float4*)&aggf[pw][c16 * 8]     = l0;
        *(float4*)&aggf[pw][c16 * 8 + 4] = h0;
        union { __bf16 h[8]; uint4 u4; } pk;
        pk.h[0] = (__bf16)l0.x; pk.h[1] = (__bf16)l0.y; pk.h[2] = (__bf16)l0.z; pk.h[3] = (__bf16)l0.w;
        pk.h[4] = (__bf16)h0.x; pk.h[5] = (__bf16)h0.y; pk.h[6] = (__bf16)h0.z; pk.h[7] = (__bf16)h0.w;
        *(uint4*)&aggbf[pw][c16 * 8] = pk.u4;
    } else {
        // ---- fp32 fallback (round-4 structure, known spill-free) ----
        const int half = lane >> 5;
        const int col  = lane & 31;
        const float4* __restrict__ entc = (const float4*)ent + col;
        float4 acc0 = {0.f,0.f,0.f,0.f}, acc1 = acc0, acc2 = acc0, acc3 = acc0;
        #pragma unroll
        for (int u = 0; u < 8; ++u) {
            const int slot = 2 * u + half;
            const int id0 = comp[wave][0][slot];
            const int id1 = comp[wave][1][slot];
            const int id2 = comp[wave][2][slot];
            const int id3 = comp[wave][3][slot];
            if (slot < c0) { float4 v = entc[(size_t)id0 << 5]; acc0.x += v.x; acc0.y += v.y; acc0.z += v.z; acc0.w += v.w; }
            if (slot < c1) { float4 v = entc[(size_t)id1 << 5]; acc1.x += v.x; acc1.y += v.y; acc1.z += v.z; acc1.w += v.w; }
            if (slot < c2) { float4 v = entc[(size_t)id2 << 5]; acc2.x += v.x; acc2.y += v.y; acc2.z += v.z; acc2.w += v.w; }
            if (slot < c3) { float4 v = entc[(size_t)id3 << 5]; acc3.x += v.x; acc3.y += v.y; acc3.z += v.z; acc3.w += v.w; }
        }
        #pragma unroll
        for (int i = 0; i < 4; ++i) {
            float4 a = (i == 0) ? acc0 : (i == 1) ? acc1 : (i == 2) ? acc2 : acc3;
            const int cnt = (i == 0) ? c0 : (i == 1) ? c1 : (i == 2) ? c2 : c3;
            a.x += __shfl_xor(a.x, 32); a.y += __shfl_xor(a.y, 32);
            a.z += __shfl_xor(a.z, 32); a.w += __shfl_xor(a.w, 32);
            const float inv = 1.0f / (float)(cnt > 1 ? cnt : 1);
            a.x *= inv; a.y *= inv; a.z *= inv; a.w *= inv;
            if (half == 0) {
                const int p = wave * 4 + i;
                *(float4*)&aggf[p][col * 4] = a;
                union { __bf16 h[4]; uint2 u2; } pk;
                pk.h[0] = (__bf16)a.x; pk.h[1] = (__bf16)a.y;
                pk.h[2] = (__bf16)a.z; pk.h[3] = (__bf16)a.w;
                *(uint2*)&aggbf[p][col * 4] = pk.u2;
            }
        }
    }
    __syncthreads();

    if (wave != 0) return;

    // ---- MLP for all 16 paths via MFMA (wave 0) ----
    const int m    = lane & 15;
    const int quad = lane >> 4;

    bf16x8_t afr[4];
    #pragma unroll
    for (int st = 0; st < 4; ++st)
        afr[st] = *(const bf16x8_t*)&aggbf[m][st * 32 + quad * 8];

    float xp[4] = {0.f, 0.f, 0.f, 0.f};
    #pragma unroll
    for (int t = 0; t < 4; ++t) {
        const int n = t * 16 + m;
        const float b1v = b1[n];
        f32x4_t acc = {b1v, b1v, b1v, b1v};
        const __bf16* bp = w1t + n * D_DIM + quad * 8;
        #pragma unroll
        for (int st = 0; st < 4; ++st) {
            bf16x8_t bfr = *(const bf16x8_t*)(bp + st * 32);
            acc = __builtin_amdgcn_mfma_f32_16x16x32_bf16(afr[st], bfr, acc, 0, 0, 0);
        }
        const float w2v = W2[n];
        #pragma unroll
        for (int r = 0; r < 4; ++r) {
            float h = acc[r] > 0.f ? acc[r] : 0.f;
            xp[r] += h * w2v;
        }
    }
    #pragma unroll
    for (int off = 1; off < 16; off <<= 1) {
        #pragma unroll
        for (int r = 0; r < 4; ++r) xp[r] += __shfl_xor(xp[r], off);
    }

    int myc[4]; int localv = 0;
    #pragma unroll
    for (int r = 0; r < 4; ++r) { myc[r] = cnts[quad * 4 + r]; localv += (myc[r] > 0); }
    int nv = localv + __shfl_xor(localv, 16);
    nv += __shfl_xor(nv, 32);
    const float invnv = 1.0f / (float)(nv > 1 ? nv : 1);
    const float b2v = b2[0];

    float wv[4];
    #pragma unroll
    for (int r = 0; r < 4; ++r) {
        float x = xp[r] + b2v;
        float w = 1.0f / (1.0f + __expf(-x));
        wv[r] = (myc[r] > 0) ? w * invnv : 0.f;
    }

    float fx = 0.f, fy = 0.f;
    #pragma unroll
    for (int p = 0; p < P_PATHS; ++p) {
        float wp = __shfl(wv[p & 3], (p >> 2) << 4);
        float2 a = *(const float2*)&aggf[p][2 * lane];
        fx += wp * a.x; fy += wp * a.y;
    }
    // single-use output stream: nontemporal (keep L2 for table rows)
    const int row = sids[s];
    union { float2 f2; unsigned long long u; } ost;
    ost.f2 = make_float2(fx, fy);
    __builtin_nontemporal_store(ost.u,
        (unsigned long long*)&out[(size_t)row * D_DIM + 2 * lane]);
}

extern "C" void kernel_launch(void* const* d_in, const int* in_sizes, int n_in,
                              void* d_out, int out_size, void* d_ws, size_t ws_size,
                              hipStream_t stream)
{
    const float* ent  = (const float*)d_in[0];
    const float* W1   = (const float*)d_in[1];
    const float* b1   = (const float*)d_in[2];
    const float* W2   = (const float*)d_in[3];
    const float* b2   = (const float*)d_in[4];
    const int*   sids = (const int*)d_in[5];
    const int*   eids = (const int*)d_in[6];
    const void*  emsk = (const void*)d_in[7];
    float* out = (float*)d_out;

    const int ND   = in_sizes[0];                     // N*D elements of entity table
    const int nent = ND / D_DIM;                      // N (pad row index)
    __bf16* w1t_ws = (__bf16*)d_ws;                   // 16 KB
    __bf16* entbf  = (__bf16*)((char*)d_ws + 16384);  // 2*(ND + D) bytes (incl. pad row)
    const bool useBf16 = (ws_size >= 16384 + ((size_t)ND + D_DIM) * 2)
                         && ((ND & 3) == 0) && ((out_size & 3) == 0);

    if (useBf16) {
        const int n4 = ND >> 2, o4 = out_size >> 2;
        const int mx = n4 > o4 ? n4 : o4;
        prep_fused_kernel<<<(mx + 255) / 256, 256, 0, stream>>>(ent, W1, entbf, w1t_ws,
                                                                out, n4, o4);
        PathGuidedAggregator_kernel<true><<<S_NODES, 256, 0, stream>>>(
            ent, (const __bf16*)entbf, b1, W2, b2, sids, eids, emsk,
            (const __bf16*)w1t_ws, out, nent);
    } else {
        hipMemsetAsync(d_out, 0, (size_t)out_size * sizeof(float), stream);
        prep_w1_kernel<<<32, 256, 0, stream>>>(W1, w1t_ws);
        PathGuidedAggregator_kernel<false><<<S_NODES, 256, 0, stream>>>(
            ent, (const __bf16*)entbf, b1, W2, b2, sids, eids, emsk,
            (const __bf16*)w1t_ws, out, nent);
    }
}

// Round 9
// 162.960 us; speedup vs baseline: 1.0160x; 1.0160x over previous
//
#include <hip/hip_runtime.h>
#include <hip/hip_bf16.h>

#define S_NODES 8192
#define P_PATHS 16
#define K_EP    16
#define D_DIM   128
#define H_DIM   64

typedef __bf16 bf16x8_t __attribute__((ext_vector_type(8)));
typedef float  f32x4_t  __attribute__((ext_vector_type(4)));

// LDS strides (elements per row), hot accesses <=2-way bank aliased (free):
#define AGGF_STRIDE  132   // floats
#define AGGBF_STRIDE 136   // bf16; rows 272B, 16B-aligned for b128 A-frag reads

// ---- fused prep: out=0, entity fp32->bf16 (+1 zero pad row), W1 -> W1^T bf16 ----
// R15: CACHED loads/stores (R14's NT here cost ~4.4us: prep is a pure streaming
// kernel already at BW; NT only disrupted it). NT stays in the MAIN kernel where
// it measurably helped (-2.5us, ids/mask pollution removal).
__global__ __launch_bounds__(256)
void prep_fused_kernel(const float* __restrict__ ent, const float* __restrict__ W1,
                       __bf16* __restrict__ entbf, __bf16* __restrict__ w1t,
                       float4* __restrict__ out4, int n4, int o4)
{
    const int i = blockIdx.x * 256 + threadIdx.x;
    if (i < n4) {
        float4 v = ((const float4*)ent)[i];
        union { __bf16 h[4]; uint2 u; } pk;
        pk.h[0] = (__bf16)v.x; pk.h[1] = (__bf16)v.y;
        pk.h[2] = (__bf16)v.z; pk.h[3] = (__bf16)v.w;
        ((uint2*)entbf)[i] = pk.u;
    }
    if (i < 32)  // zero pad row at entity index N (256 B)
        ((uint2*)entbf)[n4 + i] = make_uint2(0u, 0u);
    if (i < o4) out4[i] = make_float4(0.f, 0.f, 0.f, 0.f);
    if (i < D_DIM * H_DIM) {
        const int n = i >> 7, d = i & 127;
        w1t[i] = (__bf16)W1[d * H_DIM + n];
    }
}

// ---- fallback-path prep ----
__global__ __launch_bounds__(256)
void prep_w1_kernel(const float* __restrict__ W1, __bf16* __restrict__ w1t)
{
    const int idx = blockIdx.x * 256 + threadIdx.x;   // 32 x 256 = 8192
    const int n = idx >> 7, d = idx & 127;
    w1t[idx] = (__bf16)W1[d * H_DIM + n];
}

// unpack a 16B bf16x8 chunk into two fp32 float4 accumulators
__device__ __forceinline__ void acc_row(float4& lo, float4& hi, uint4 r)
{
    lo.x += __uint_as_float(r.x << 16); lo.y += __uint_as_float(r.x & 0xffff0000u);
    lo.z += __uint_as_float(r.y << 16); lo.w += __uint_as_float(r.y & 0xffff0000u);
    hi.x += __uint_as_float(r.z << 16); hi.y += __uint_as_float(r.z & 0xffff0000u);
    hi.z += __uint_as_float(r.w << 16); hi.w += __uint_as_float(r.w & 0xffff0000u);
}

template<bool USE_BF16>
__global__ __launch_bounds__(256, 4)
void PathGuidedAggregator_kernel(const float*  __restrict__ ent,
                                 const __bf16* __restrict__ entbf,  // bf16 table + zero pad row (ws)
                                 const float*  __restrict__ b1,
                                 const float*  __restrict__ W2,
                                 const float*  __restrict__ b2,
                                 const int*    __restrict__ sids,
                                 const int*    __restrict__ eids,
                                 const void*   __restrict__ emask,
                                 const __bf16* __restrict__ w1t,    // [H][D] bf16 (ws)
                                 float*        __restrict__ out,
                                 int nent)                          // pad row index
{
    __shared__ float  aggf [P_PATHS][AGGF_STRIDE];   // fp32 agg (epilogue w*agg)
    __shared__ __bf16 aggbf[P_PATHS][AGGBF_STRIDE];  // bf16 agg (MFMA A operand)
    __shared__ int    cnts[P_PATHS];
    __shared__ int    comp[4][4][K_EP];              // fallback + bf16 id staging

    const int s    = blockIdx.x;
    const int tid  = threadIdx.x;
    const int wave = tid >> 6;
    const int lane = tid & 63;

    // ---- runtime detection of bool-mask storage: int32 / uint8 / float32 ----
    // (probe line is re-read by every block -> keep it cached, NOT nontemporal)
    const unsigned int* mw = (const unsigned int*)emask;
    unsigned int probe = mw[lane];
    const bool floatMask = (__ballot(probe == 0x3F800000u) != 0ULL);
    const bool byteMask  = !floatMask && (__ballot(probe > 1u) != 0ULL);

    // ---- one coalesced 64-lane load covers ids+mask for this wave's 4 paths ----
    // ids/mask are single-use streams (33.6 MB/launch) -> NONTEMPORAL loads so they
    // don't evict gather-table rows from the 4MB/XCD L2. Measured R14: main kernel
    // 47.1 -> 44.6us, FETCH 121 -> 119.9MB.
    const int base = (s * P_PATHS + wave * 4) * K_EP;
    const int idv  = __builtin_nontemporal_load(eids + base + lane);
    int mk;
    if (floatMask)     mk = (__builtin_nontemporal_load(((const float*)emask) + base + lane) != 0.0f);
    else if (byteMask) mk = __builtin_nontemporal_load(((const unsigned char*)emask) + base + lane);
    else               mk = __builtin_nontemporal_load(((const int*)emask) + base + lane);
    const unsigned long long bits_all = __ballot(mk != 0);

    const int k16  = lane & 15;
    const int pgrp = lane >> 4;

    // compact valid ids; pad slots point at the zero row (bf16 path) so loads need no guards
    const unsigned int bits_p = (unsigned int)((bits_all >> (16 * pgrp)) & 0xFFFFu);
    comp[wave][pgrp][k16] = USE_BF16 ? nent : 0;
    if (mk) comp[wave][pgrp][__popc(bits_p & ((1u << k16) - 1u))] = idv;
    if (lane < 4) cnts[wave * 4 + lane] = __popc((unsigned int)((bits_all >> (16 * lane)) & 0xFFFFu));

    const int c0 = __popc((unsigned int)( bits_all        & 0xFFFFu));
    const int c1 = __popc((unsigned int)((bits_all >> 16) & 0xFFFFu));
    const int c2 = __popc((unsigned int)((bits_all >> 32) & 0xFFFFu));
    const int c3 = __popc((unsigned int)((bits_all >> 48) & 0xFFFFu));

    const int q   = lane >> 4;       // quarter: owns slots q, q+4, q+8, q+12
    const int c16 = lane & 15;

    if constexpr (USE_BF16) {
        // ---- rotated-butterfly gather (R1 champion) + 16-load block (R13/R14).
        // Depth conclusion (R13/R14 + Little's law): per-wave outstanding depth is
        // NOT the limiter; the kernel is pinned at ~2.85 TB/s L2-miss service rate
        // for random 256B granules (dur == hbm_bytes/rate across all variants).
        // Accumulator j of quarter q holds path (q^j); cross-quarter merge is a
        // 2-stage reduce-scatter butterfly (24 shuffles, zero selects).
        const uint4* __restrict__ entb = (const uint4*)entbf;
        float4 l0 = {0,0,0,0}, h0 = l0, l1 = l0, h1 = l0, l2 = l0, h2 = l0, l3 = l0, h3 = l0;

        uint4 rb[16];
        #pragma unroll
        for (int sl = 0; sl < 4; ++sl) {
            const int slot = q + 4 * sl;
            rb[4 * sl + 0] = entb[(size_t)comp[wave][q    ][slot] * 16 + c16];
            rb[4 * sl + 1] = entb[(size_t)comp[wave][q ^ 1][slot] * 16 + c16];
            rb[4 * sl + 2] = entb[(size_t)comp[wave][q ^ 2][slot] * 16 + c16];
            rb[4 * sl + 3] = entb[(size_t)comp[wave][q ^ 3][slot] * 16 + c16];
        }
        __builtin_amdgcn_sched_barrier(0);
        #pragma unroll
        for (int sl = 0; sl < 4; ++sl) {
            acc_row(l0, h0, rb[4 * sl + 0]);
            acc_row(l1, h1, rb[4 * sl + 1]);
            acc_row(l2, h2, rb[4 * sl + 2]);
            acc_row(l3, h3, rb[4 * sl + 3]);
        }
        // reduce-scatter stage 1 (xor 16)
        l0.x += __shfl_xor(l1.x, 16); l0.y += __shfl_xor(l1.y, 16);
        l0.z += __shfl_xor(l1.z, 16); l0.w += __shfl_xor(l1.w, 16);
        h0.x += __shfl_xor(h1.x, 16); h0.y += __shfl_xor(h1.y, 16);
        h0.z += __shfl_xor(h1.z, 16); h0.w += __shfl_xor(h1.w, 16);
        l2.x += __shfl_xor(l3.x, 16); l2.y += __shfl_xor(l3.y, 16);
        l2.z += __shfl_xor(l3.z, 16); l2.w += __shfl_xor(l3.w, 16);
        h2.x += __shfl_xor(h3.x, 16); h2.y += __shfl_xor(h3.y, 16);
        h2.z += __shfl_xor(h3.z, 16); h2.w += __shfl_xor(h3.w, 16);
        // reduce-scatter stage 2 (xor 32)
        l0.x += __shfl_xor(l2.x, 32); l0.y += __shfl_xor(l2.y, 32);
        l0.z += __shfl_xor(l2.z, 32); l0.w += __shfl_xor(l2.w, 32);
        h0.x += __shfl_xor(h2.x, 32); h0.y += __shfl_xor(h2.y, 32);
        h0.z += __shfl_xor(h2.z, 32); h0.w += __shfl_xor(h2.w, 32);

        // quarter q now holds the full sum of path q in (l0, h0)
        const int   cq   = __popc((unsigned int)((bits_all >> (16 * q)) & 0xFFFFu));
        const float invq = 1.0f / (float)(cq > 1 ? cq : 1);
        l0.x *= invq; l0.y *= invq; l0.z *= invq; l0.w *= invq;
        h0.x *= invq; h0.y *= invq; h0.z *= invq; h0.w *= invq;
        const int pw = wave * 4 + q;
        *(float4*)&aggf[pw][c16 * 8]     = l0;
        *(float4*)&aggf[pw][c16 * 8 + 4] = h0;
        union { __bf16 h[8]; uint4 u4; } pk;
        pk.h[0] = (__bf16)l0.x; pk.h[1] = (__bf16)l0.y; pk.h[2] = (__bf16)l0.z; pk.h[3] = (__bf16)l0.w;
        pk.h[4] = (__bf16)h0.x; pk.h[5] = (__bf16)h0.y; pk.h[6] = (__bf16)h0.z; pk.h[7] = (__bf16)h0.w;
        *(uint4*)&aggbf[pw][c16 * 8] = pk.u4;
    } else {
        // ---- fp32 fallback (round-4 structure, known spill-free) ----
        const int half = lane >> 5;
        const int col  = lane & 31;
        const float4* __restrict__ entc = (const float4*)ent + col;
        float4 acc0 = {0.f,0.f,0.f,0.f}, acc1 = acc0, acc2 = acc0, acc3 = acc0;
        #pragma unroll
        for (int u = 0; u < 8; ++u) {
            const int slot = 2 * u + half;
            const int id0 = comp[wave][0][slot];
            const int id1 = comp[wave][1][slot];
            const int id2 = comp[wave][2][slot];
            const int id3 = comp[wave][3][slot];
            if (slot < c0) { float4 v = entc[(size_t)id0 << 5]; acc0.x += v.x; acc0.y += v.y; acc0.z += v.z; acc0.w += v.w; }
            if (slot < c1) { float4 v = entc[(size_t)id1 << 5]; acc1.x += v.x; acc1.y += v.y; acc1.z += v.z; acc1.w += v.w; }
            if (slot < c2) { float4 v = entc[(size_t)id2 << 5]; acc2.x += v.x; acc2.y += v.y; acc2.z += v.z; acc2.w += v.w; }
            if (slot < c3) { float4 v = entc[(size_t)id3 << 5]; acc3.x += v.x; acc3.y += v.y; acc3.z += v.z; acc3.w += v.w; }
        }
        #pragma unroll
        for (int i = 0; i < 4; ++i) {
            float4 a = (i == 0) ? acc0 : (i == 1) ? acc1 : (i == 2) ? acc2 : acc3;
            const int cnt = (i == 0) ? c0 : (i == 1) ? c1 : (i == 2) ? c2 : c3;
            a.x += __shfl_xor(a.x, 32); a.y += __shfl_xor(a.y, 32);
            a.z += __shfl_xor(a.z, 32); a.w += __shfl_xor(a.w, 32);
            const float inv = 1.0f / (float)(cnt > 1 ? cnt : 1);
            a.x *= inv; a.y *= inv; a.z *= inv; a.w *= inv;
            if (half == 0) {
                const int p = wave * 4 + i;
                *(float4*)&aggf[p][col * 4] = a;
                union { __bf16 h[4]; uint2 u2; } pk;
                pk.h[0] = (__bf16)a.x; pk.h[1] = (__bf16)a.y;
                pk.h[2] = (__bf16)a.z; pk.h[3] = (__bf16)a.w;
                *(uint2*)&aggbf[p][col * 4] = pk.u2;
            }
        }
    }
    __syncthreads();

    if (wave != 0) return;

    // ---- MLP for all 16 paths via MFMA (wave 0) ----
    const int m    = lane & 15;
    const int quad = lane >> 4;

    bf16x8_t afr[4];
    #pragma unroll
    for (int st = 0; st < 4; ++st)
        afr[st] = *(const bf16x8_t*)&aggbf[m][st * 32 + quad * 8];

    float xp[4] = {0.f, 0.f, 0.f, 0.f};
    #pragma unroll
    for (int t = 0; t < 4; ++t) {
        const int n = t * 16 + m;
        const float b1v = b1[n];
        f32x4_t acc = {b1v, b1v, b1v, b1v};
        const __bf16* bp = w1t + n * D_DIM + quad * 8;
        #pragma unroll
        for (int st = 0; st < 4; ++st) {
            bf16x8_t bfr = *(const bf16x8_t*)(bp + st * 32);
            acc = __builtin_amdgcn_mfma_f32_16x16x32_bf16(afr[st], bfr, acc, 0, 0, 0);
        }
        const float w2v = W2[n];
        #pragma unroll
        for (int r = 0; r < 4; ++r) {
            float h = acc[r] > 0.f ? acc[r] : 0.f;
            xp[r] += h * w2v;
        }
    }
    #pragma unroll
    for (int off = 1; off < 16; off <<= 1) {
        #pragma unroll
        for (int r = 0; r < 4; ++r) xp[r] += __shfl_xor(xp[r], off);
    }

    int myc[4]; int localv = 0;
    #pragma unroll
    for (int r = 0; r < 4; ++r) { myc[r] = cnts[quad * 4 + r]; localv += (myc[r] > 0); }
    int nv = localv + __shfl_xor(localv, 16);
    nv += __shfl_xor(nv, 32);
    const float invnv = 1.0f / (float)(nv > 1 ? nv : 1);
    const float b2v = b2[0];

    float wv[4];
    #pragma unroll
    for (int r = 0; r < 4; ++r) {
        float x = xp[r] + b2v;
        float w = 1.0f / (1.0f + __expf(-x));
        wv[r] = (myc[r] > 0) ? w * invnv : 0.f;
    }

    float fx = 0.f, fy = 0.f;
    #pragma unroll
    for (int p = 0; p < P_PATHS; ++p) {
        float wp = __shfl(wv[p & 3], (p >> 2) << 4);
        float2 a = *(const float2*)&aggf[p][2 * lane];
        fx += wp * a.x; fy += wp * a.y;
    }
    // single-use output stream: nontemporal (keep L2 for table rows)
    const int row = sids[s];
    union { float2 f2; unsigned long long u; } ost;
    ost.f2 = make_float2(fx, fy);
    __builtin_nontemporal_store(ost.u,
        (unsigned long long*)&out[(size_t)row * D_DIM + 2 * lane]);
}

extern "C" void kernel_launch(void* const* d_in, const int* in_sizes, int n_in,
                              void* d_out, int out_size, void* d_ws, size_t ws_size,
                              hipStream_t stream)
{
    const float* ent  = (const float*)d_in[0];
    const float* W1   = (const float*)d_in[1];
    const float* b1   = (const float*)d_in[2];
    const float* W2   = (const float*)d_in[3];
    const float* b2   = (const float*)d_in[4];
    const int*   sids = (const int*)d_in[5];
    const int*   eids = (const int*)d_in[6];
    const void*  emsk = (const void*)d_in[7];
    float* out = (float*)d_out;

    const int ND   = in_sizes[0];                     // N*D elements of entity table
    const int nent = ND / D_DIM;                      // N (pad row index)
    __bf16* w1t_ws = (__bf16*)d_ws;                   // 16 KB
    __bf16* entbf  = (__bf16*)((char*)d_ws + 16384);  // 2*(ND + D) bytes (incl. pad row)
    const bool useBf16 = (ws_size >= 16384 + ((size_t)ND + D_DIM) * 2)
                         && ((ND & 3) == 0) && ((out_size & 3) == 0);

    if (useBf16) {
        const int n4 = ND >> 2, o4 = out_size >> 2;
        const int mx = n4 > o4 ? n4 : o4;
        prep_fused_kernel<<<(mx + 255) / 256, 256, 0, stream>>>(ent, W1, entbf, w1t_ws,
                                                                (float4*)out, n4, o4);
        PathGuidedAggregator_kernel<true><<<S_NODES, 256, 0, stream>>>(
            ent, (const __bf16*)entbf, b1, W2, b2, sids, eids, emsk,
            (const __bf16*)w1t_ws, out, nent);
    } else {
        hipMemsetAsync(d_out, 0, (size_t)out_size * sizeof(float), stream);
        prep_w1_kernel<<<32, 256, 0, stream>>>(W1, w1t_ws);
        PathGuidedAggregator_kernel<false><<<S_NODES, 256, 0, stream>>>(
            ent, (const __bf16*)entbf, b1, W2, b2, sids, eids, emsk,
            (const __bf16*)w1t_ws, out, nent);
    }
}

// Round 10
// 159.405 us; speedup vs baseline: 1.0387x; 1.0223x over previous
//
#include <hip/hip_runtime.h>
#include <hip/hip_bf16.h>

#define S_NODES 8192
#define P_PATHS 16
#define K_EP    16
#define D_DIM   128
#define H_DIM   64

typedef __bf16 bf16x8_t __attribute__((ext_vector_type(8)));
typedef float  f32x4_t  __attribute__((ext_vector_type(4)));

// LDS strides (elements per row), hot accesses <=2-way bank aliased (free):
#define AGGF_STRIDE  132   // floats
#define AGGBF_STRIDE 136   // bf16; rows 272B, 16B-aligned for b128 A-frag reads

// ---- fused prep: out=0, entity fp32 -> int8 rows (128B) + per-row dequant scale,
// W1 -> W1^T bf16. R16: int8 table halves gather bytes AND shrinks the working set
// to 12.9MB (~L2-resident per XCD) -- attacks the measured ~2.8 TB/s L2-miss rate
// pin where concurrency levers are exhausted. Per-row scale (127/rowmax) beats fp8
// e4m3 ~2-3x on N(0,1) data accuracy-per-byte.
__global__ __launch_bounds__(256)
void prep_q8_kernel(const float* __restrict__ ent, const float* __restrict__ W1,
                    signed char* __restrict__ q8, float* __restrict__ scales,
                    __bf16* __restrict__ w1t, float4* __restrict__ out4,
                    int nent, int o4)
{
    const int tid = threadIdx.x;
    const int b   = blockIdx.x;

    // ---- int8 row quantization: 32 lanes per row, 8 rows per block ----
    const int r   = b * 8 + (tid >> 5);
    const int col = tid & 31;
    if (r < nent) {
        float4 v = ((const float4*)ent)[r * 32 + col];
        float m = fmaxf(fmaxf(fabsf(v.x), fabsf(v.y)), fmaxf(fabsf(v.z), fabsf(v.w)));
        // row-max butterfly (offsets 1..16 stay inside each 32-lane half of the wave)
        m = fmaxf(m, __shfl_xor(m, 1));
        m = fmaxf(m, __shfl_xor(m, 2));
        m = fmaxf(m, __shfl_xor(m, 4));
        m = fmaxf(m, __shfl_xor(m, 8));
        m = fmaxf(m, __shfl_xor(m, 16));
        const float inv = (m > 0.f) ? 127.f / m : 0.f;
        const int q0 = (int)rintf(v.x * inv);
        const int q1 = (int)rintf(v.y * inv);
        const int q2 = (int)rintf(v.z * inv);
        const int q3 = (int)rintf(v.w * inv);
        const unsigned int pk = (q0 & 0xff) | ((q1 & 0xff) << 8) |
                                ((q2 & 0xff) << 16) | ((q3 & 0xff) << 24);
        ((unsigned int*)q8)[r * 32 + col] = pk;
        if (col == 0) scales[r] = m * (1.f / 127.f);
    }
    // pad row at index nent: zeros, scale 0 (gather pad slots contribute 0)
    if (b == 0 && tid < 32) {
        ((unsigned int*)q8)[nent * 32 + tid] = 0u;
        if (tid == 0) scales[nent] = 0.f;
    }
    const int i = b * 256 + tid;
    if (i < o4) out4[i] = make_float4(0.f, 0.f, 0.f, 0.f);
    if (i < D_DIM * H_DIM) {
        const int n = i >> 7, d = i & 127;
        w1t[i] = (__bf16)W1[d * H_DIM + n];
    }
}

// ---- fallback-path prep ----
__global__ __launch_bounds__(256)
void prep_w1_kernel(const float* __restrict__ W1, __bf16* __restrict__ w1t)
{
    const int idx = blockIdx.x * 256 + threadIdx.x;   // 32 x 256 = 8192
    const int n = idx >> 7, d = idx & 127;
    w1t[idx] = (__bf16)W1[d * H_DIM + n];
}

// dequant-accumulate one 8B int8 chunk (8 dims) into two fp32 float4 accumulators
__device__ __forceinline__ void acc_q8(float4& lo, float4& hi, uint2 r, float sc)
{
    lo.x += sc * (float)(int)(signed char)( r.x        & 0xff);
    lo.y += sc * (float)(int)(signed char)((r.x >>  8) & 0xff);
    lo.z += sc * (float)(int)(signed char)((r.x >> 16) & 0xff);
    lo.w += sc * (float)((int)r.x >> 24);
    hi.x += sc * (float)(int)(signed char)( r.y        & 0xff);
    hi.y += sc * (float)(int)(signed char)((r.y >>  8) & 0xff);
    hi.z += sc * (float)(int)(signed char)((r.y >> 16) & 0xff);
    hi.w += sc * (float)((int)r.y >> 24);
}

template<bool USE_Q8>
__global__ __launch_bounds__(256, 4)
void PathGuidedAggregator_kernel(const float*  __restrict__ ent,
                                 const signed char* __restrict__ entq,  // int8 rows (ws)
                                 const float*  __restrict__ scales,     // per-row dequant (ws)
                                 const float*  __restrict__ b1,
                                 const float*  __restrict__ W2,
                                 const float*  __restrict__ b2,
                                 const int*    __restrict__ sids,
                                 const int*    __restrict__ eids,
                                 const void*   __restrict__ emask,
                                 const __bf16* __restrict__ w1t,        // [H][D] bf16 (ws)
                                 float*        __restrict__ out,
                                 int nent)                              // pad row index
{
    __shared__ float  aggf [P_PATHS][AGGF_STRIDE];   // fp32 agg (epilogue w*agg)
    __shared__ __bf16 aggbf[P_PATHS][AGGBF_STRIDE];  // bf16 agg (MFMA A operand)
    __shared__ int    cnts[P_PATHS];
    __shared__ int    comp[4][4][K_EP];              // fallback + q8 id staging

    const int s    = blockIdx.x;
    const int tid  = threadIdx.x;
    const int wave = tid >> 6;
    const int lane = tid & 63;

    // ---- runtime detection of bool-mask storage: int32 / uint8 / float32 ----
    const unsigned int* mw = (const unsigned int*)emask;
    unsigned int probe = mw[lane];
    const bool floatMask = (__ballot(probe == 0x3F800000u) != 0ULL);
    const bool byteMask  = !floatMask && (__ballot(probe > 1u) != 0ULL);

    // ids/mask are single-use streams -> NONTEMPORAL (measured R14: -2.5us main)
    const int base = (s * P_PATHS + wave * 4) * K_EP;
    const int idv  = __builtin_nontemporal_load(eids + base + lane);
    int mk;
    if (floatMask)     mk = (__builtin_nontemporal_load(((const float*)emask) + base + lane) != 0.0f);
    else if (byteMask) mk = __builtin_nontemporal_load(((const unsigned char*)emask) + base + lane);
    else               mk = __builtin_nontemporal_load(((const int*)emask) + base + lane);
    const unsigned long long bits_all = __ballot(mk != 0);

    const int k16  = lane & 15;
    const int pgrp = lane >> 4;

    // compact valid ids; pad slots point at the zero row (q8 path) so loads need no guards
    const unsigned int bits_p = (unsigned int)((bits_all >> (16 * pgrp)) & 0xFFFFu);
    comp[wave][pgrp][k16] = USE_Q8 ? nent : 0;
    if (mk) comp[wave][pgrp][__popc(bits_p & ((1u << k16) - 1u))] = idv;
    if (lane < 4) cnts[wave * 4 + lane] = __popc((unsigned int)((bits_all >> (16 * lane)) & 0xFFFFu));

    const int c0 = __popc((unsigned int)( bits_all        & 0xFFFFu));
    const int c1 = __popc((unsigned int)((bits_all >> 16) & 0xFFFFu));
    const int c2 = __popc((unsigned int)((bits_all >> 32) & 0xFFFFu));
    const int c3 = __popc((unsigned int)((bits_all >> 48) & 0xFFFFu));

    const int q   = lane >> 4;       // quarter: owns slots q, q+4, q+8, q+12
    const int c16 = lane & 15;

    if constexpr (USE_Q8) {
        // ---- int8 gather: rotated-butterfly structure (R1 champion). Quarter's 16
        // lanes x uint2(8B) = one contiguous 128B row per issue. Per-row scale
        // broadcast-loaded from the 400KB L2-hot scales array. Accumulator j of
        // quarter q holds path (q^j); merge = 2-stage reduce-scatter butterfly.
        const uint2* __restrict__ entq2 = (const uint2*)entq;
        float4 l0 = {0,0,0,0}, h0 = l0, l1 = l0, h1 = l0, l2 = l0, h2 = l0, l3 = l0, h3 = l0;

        uint2 rb[16]; float sc[16];
        #pragma unroll
        for (int sl = 0; sl < 4; ++sl) {
            const int slot = q + 4 * sl;
            const int i0 = comp[wave][q    ][slot];
            const int i1 = comp[wave][q ^ 1][slot];
            const int i2 = comp[wave][q ^ 2][slot];
            const int i3 = comp[wave][q ^ 3][slot];
            rb[4 * sl + 0] = entq2[(size_t)i0 * 16 + c16];  sc[4 * sl + 0] = scales[i0];
            rb[4 * sl + 1] = entq2[(size_t)i1 * 16 + c16];  sc[4 * sl + 1] = scales[i1];
            rb[4 * sl + 2] = entq2[(size_t)i2 * 16 + c16];  sc[4 * sl + 2] = scales[i2];
            rb[4 * sl + 3] = entq2[(size_t)i3 * 16 + c16];  sc[4 * sl + 3] = scales[i3];
        }
        __builtin_amdgcn_sched_barrier(0);
        #pragma unroll
        for (int sl = 0; sl < 4; ++sl) {
            acc_q8(l0, h0, rb[4 * sl + 0], sc[4 * sl + 0]);
            acc_q8(l1, h1, rb[4 * sl + 1], sc[4 * sl + 1]);
            acc_q8(l2, h2, rb[4 * sl + 2], sc[4 * sl + 2]);
            acc_q8(l3, h3, rb[4 * sl + 3], sc[4 * sl + 3]);
        }
        // reduce-scatter stage 1 (xor 16)
        l0.x += __shfl_xor(l1.x, 16); l0.y += __shfl_xor(l1.y, 16);
        l0.z += __shfl_xor(l1.z, 16); l0.w += __shfl_xor(l1.w, 16);
        h0.x += __shfl_xor(h1.x, 16); h0.y += __shfl_xor(h1.y, 16);
        h0.z += __shfl_xor(h1.z, 16); h0.w += __shfl_xor(h1.w, 16);
        l2.x += __shfl_xor(l3.x, 16); l2.y += __shfl_xor(l3.y, 16);
        l2.z += __shfl_xor(l3.z, 16); l2.w += __shfl_xor(l3.w, 16);
        h2.x += __shfl_xor(h3.x, 16); h2.y += __shfl_xor(h3.y, 16);
        h2.z += __shfl_xor(h3.z, 16); h2.w += __shfl_xor(h3.w, 16);
        // reduce-scatter stage 2 (xor 32)
        l0.x += __shfl_xor(l2.x, 32); l0.y += __shfl_xor(l2.y, 32);
        l0.z += __shfl_xor(l2.z, 32); l0.w += __shfl_xor(l2.w, 32);
        h0.x += __shfl_xor(h2.x, 32); h0.y += __shfl_xor(h2.y, 32);
        h0.z += __shfl_xor(h2.z, 32); h0.w += __shfl_xor(h2.w, 32);

        // quarter q now holds the full sum of path q in (l0, h0)
        const int   cq   = __popc((unsigned int)((bits_all >> (16 * q)) & 0xFFFFu));
        const float invq = 1.0f / (float)(cq > 1 ? cq : 1);
        l0.x *= invq; l0.y *= invq; l0.z *= invq; l0.w *= invq;
        h0.x *= invq; h0.y *= invq; h0.z *= invq; h0.w *= invq;
        const int pw = wave * 4 + q;
        *(float4*)&aggf[pw][c16 * 8]     = l0;
        *(float4*)&aggf[pw][c16 * 8 + 4] = h0;
        union { __bf16 h[8]; uint4 u4; } pk;
        pk.h[0] = (__bf16)l0.x; pk.h[1] = (__bf16)l0.y; pk.h[2] = (__bf16)l0.z; pk.h[3] = (__bf16)l0.w;
        pk.h[4] = (__bf16)h0.x; pk.h[5] = (__bf16)h0.y; pk.h[6] = (__bf16)h0.z; pk.h[7] = (__bf16)h0.w;
        *(uint4*)&aggbf[pw][c16 * 8] = pk.u4;
    } else {
        // ---- fp32 fallback (round-4 structure, known spill-free) ----
        const int half = lane >> 5;
        const int col  = lane & 31;
        const float4* __restrict__ entc = (const float4*)ent + col;
        float4 acc0 = {0.f,0.f,0.f,0.f}, acc1 = acc0, acc2 = acc0, acc3 = acc0;
        #pragma unroll
        for (int u = 0; u < 8; ++u) {
            const int slot = 2 * u + half;
            const int id0 = comp[wave][0][slot];
            const int id1 = comp[wave][1][slot];
            const int id2 = comp[wave][2][slot];
            const int id3 = comp[wave][3][slot];
            if (slot < c0) { float4 v = entc[(size_t)id0 << 5]; acc0.x += v.x; acc0.y += v.y; acc0.z += v.z; acc0.w += v.w; }
            if (slot < c1) { float4 v = entc[(size_t)id1 << 5]; acc1.x += v.x; acc1.y += v.y; acc1.z += v.z; acc1.w += v.w; }
            if (slot < c2) { float4 v = entc[(size_t)id2 << 5]; acc2.x += v.x; acc2.y += v.y; acc2.z += v.z; acc2.w += v.w; }
            if (slot < c3) { float4 v = entc[(size_t)id3 << 5]; acc3.x += v.x; acc3.y += v.y; acc3.z += v.z; acc3.w += v.w; }
        }
        #pragma unroll
        for (int i = 0; i < 4; ++i) {
            float4 a = (i == 0) ? acc0 : (i == 1) ? acc1 : (i == 2) ? acc2 : acc3;
            const int cnt = (i == 0) ? c0 : (i == 1) ? c1 : (i == 2) ? c2 : c3;
            a.x += __shfl_xor(a.x, 32); a.y += __shfl_xor(a.y, 32);
            a.z += __shfl_xor(a.z, 32); a.w += __shfl_xor(a.w, 32);
            const float inv = 1.0f / (float)(cnt > 1 ? cnt : 1);
            a.x *= inv; a.y *= inv; a.z *= inv; a.w *= inv;
            if (half == 0) {
                const int p = wave * 4 + i;
                *(float4*)&aggf[p][col * 4] = a;
                union { __bf16 h[4]; uint2 u2; } pk;
                pk.h[0] = (__bf16)a.x; pk.h[1] = (__bf16)a.y;
                pk.h[2] = (__bf16)a.z; pk.h[3] = (__bf16)a.w;
                *(uint2*)&aggbf[p][col * 4] = pk.u2;
            }
        }
    }
    __syncthreads();

    if (wave != 0) return;

    // ---- MLP for all 16 paths via MFMA (wave 0) ----
    const int m    = lane & 15;
    const int quad = lane >> 4;

    bf16x8_t afr[4];
    #pragma unroll
    for (int st = 0; st < 4; ++st)
        afr[st] = *(const bf16x8_t*)&aggbf[m][st * 32 + quad * 8];

    float xp[4] = {0.f, 0.f, 0.f, 0.f};
    #pragma unroll
    for (int t = 0; t < 4; ++t) {
        const int n = t * 16 + m;
        const float b1v = b1[n];
        f32x4_t acc = {b1v, b1v, b1v, b1v};
        const __bf16* bp = w1t + n * D_DIM + quad * 8;
        #pragma unroll
        for (int st = 0; st < 4; ++st) {
            bf16x8_t bfr = *(const bf16x8_t*)(bp + st * 32);
            acc = __builtin_amdgcn_mfma_f32_16x16x32_bf16(afr[st], bfr, acc, 0, 0, 0);
        }
        const float w2v = W2[n];
        #pragma unroll
        for (int r = 0; r < 4; ++r) {
            float h = acc[r] > 0.f ? acc[r] : 0.f;
            xp[r] += h * w2v;
        }
    }
    #pragma unroll
    for (int off = 1; off < 16; off <<= 1) {
        #pragma unroll
        for (int r = 0; r < 4; ++r) xp[r] += __shfl_xor(xp[r], off);
    }

    int myc[4]; int localv = 0;
    #pragma unroll
    for (int r = 0; r < 4; ++r) { myc[r] = cnts[quad * 4 + r]; localv += (myc[r] > 0); }
    int nv = localv + __shfl_xor(localv, 16);
    nv += __shfl_xor(nv, 32);
    const float invnv = 1.0f / (float)(nv > 1 ? nv : 1);
    const float b2v = b2[0];

    float wv[4];
    #pragma unroll
    for (int r = 0; r < 4; ++r) {
        float x = xp[r] + b2v;
        float w = 1.0f / (1.0f + __expf(-x));
        wv[r] = (myc[r] > 0) ? w * invnv : 0.f;
    }

    float fx = 0.f, fy = 0.f;
    #pragma unroll
    for (int p = 0; p < P_PATHS; ++p) {
        float wp = __shfl(wv[p & 3], (p >> 2) << 4);
        float2 a = *(const float2*)&aggf[p][2 * lane];
        fx += wp * a.x; fy += wp * a.y;
    }
    // single-use output stream: nontemporal (keep L2 for table rows)
    const int row = sids[s];
    union { float2 f2; unsigned long long u; } ost;
    ost.f2 = make_float2(fx, fy);
    __builtin_nontemporal_store(ost.u,
        (unsigned long long*)&out[(size_t)row * D_DIM + 2 * lane]);
}

extern "C" void kernel_launch(void* const* d_in, const int* in_sizes, int n_in,
                              void* d_out, int out_size, void* d_ws, size_t ws_size,
                              hipStream_t stream)
{
    const float* ent  = (const float*)d_in[0];
    const float* W1   = (const float*)d_in[1];
    const float* b1   = (const float*)d_in[2];
    const float* W2   = (const float*)d_in[3];
    const float* b2   = (const float*)d_in[4];
    const int*   sids = (const int*)d_in[5];
    const int*   eids = (const int*)d_in[6];
    const void*  emsk = (const void*)d_in[7];
    float* out = (float*)d_out;

    const int ND   = in_sizes[0];                     // N*D elements of entity table
    const int nent = ND / D_DIM;                      // N (pad row index)
    char* ws = (char*)d_ws;
    __bf16*      w1t_ws = (__bf16*)ws;                            // 16 KB
    signed char* q8     = (signed char*)(ws + 16384);             // (nent+1)*128 B
    float*       scales = (float*)(ws + 16384 + (size_t)(nent + 1) * 128);
    const size_t need   = 16384 + (size_t)(nent + 1) * 128 + (size_t)(nent + 1) * 4;
    const bool useQ8 = (ws_size >= need) && ((ND & 3) == 0) && ((out_size & 3) == 0)
                       && (ND == nent * D_DIM);

    if (useQ8) {
        const int o4 = out_size >> 2;
        int blocks = (nent + 7) / 8;
        const int zb = (o4 + 255) / 256;
        if (zb > blocks) blocks = zb;
        if (blocks < 32) blocks = 32;
        prep_q8_kernel<<<blocks, 256, 0, stream>>>(ent, W1, q8, scales, w1t_ws,
                                                   (float4*)out, nent, o4);
        PathGuidedAggregator_kernel<true><<<S_NODES, 256, 0, stream>>>(
            ent, q8, scales, b1, W2, b2, sids, eids, emsk,
            (const __bf16*)w1t_ws, out, nent);
    } else {
        hipMemsetAsync(d_out, 0, (size_t)out_size * sizeof(float), stream);
        prep_w1_kernel<<<32, 256, 0, stream>>>(W1, w1t_ws);
        PathGuidedAggregator_kernel<false><<<S_NODES, 256, 0, stream>>>(
            ent, q8, scales, b1, W2, b2, sids, eids, emsk,
            (const __bf16*)w1t_ws, out, nent);
    }
}